// Round 5
// baseline (401.904 us; speedup 1.0000x reference)
//
#include <hip/hip_runtime.h>
#include <hip/hip_bf16.h>
#include <stdint.h>

typedef unsigned short u16;
typedef unsigned int u32;
typedef __attribute__((ext_vector_type(8))) __bf16 bfrag;
typedef __attribute__((ext_vector_type(4))) float f32x4;
typedef __attribute__((ext_vector_type(16))) float f32x16;
typedef __attribute__((ext_vector_type(4))) unsigned short u16x4;

__device__ __forceinline__ u16 f2bf(float f){
  union { float f; u32 u; } v; v.f = f;
  u32 u = v.u;
  return (u16)((u + 0x7fffu + ((u >> 16) & 1u)) >> 16);
}

__device__ __forceinline__ u32 cvtpk(float a, float b){
  u32 r; asm("v_cvt_pk_bf16_f32 %0, %1, %2" : "=v"(r) : "v"(a), "v"(b)); return r;
}
__device__ __forceinline__ void swap32(u32 &a, u32 &b){
  asm volatile("v_permlane32_swap_b32 %0, %1" : "+v"(a), "+v"(b));
}

__device__ __forceinline__ void gload_lds16(const void* g, void* l){
  __builtin_amdgcn_global_load_lds(
      (__attribute__((address_space(1))) void*)(unsigned long long)g,
      (__attribute__((address_space(3))) void*)(u32)(unsigned long long)l,
      16, 0, 0);
}

// ---------------- converts ----------------
__global__ void __launch_bounds__(256) k_cvt(const float* __restrict__ s, u16* __restrict__ d, int n4){
  int i = blockIdx.x*256 + threadIdx.x;
  if (i >= n4) return;
  float4 v = ((const float4*)s)[i];
  u16x4 o; o[0]=f2bf(v.x); o[1]=f2bf(v.y); o[2]=f2bf(v.z); o[3]=f2bf(v.w);
  ((u16x4*)d)[i] = o;
}

// past_k [16][3072][128] f32 -> k_all [16][4096][128] bf16 (rows 0..3071)
__global__ void __launch_bounds__(256) k_cvt_past(const float* __restrict__ s, u16* __restrict__ d, int n4){
  int i = blockIdx.x*256 + threadIdx.x;
  if (i >= n4) return;
  int e = i*4;
  int row = e >> 7;
  int col = e & 127;
  int bh = row / 3072;
  int m = row - bh*3072;
  float4 v = ((const float4*)s)[i];
  u16x4 o; o[0]=f2bf(v.x); o[1]=f2bf(v.y); o[2]=f2bf(v.z); o[3]=f2bf(v.w);
  *(u16x4*)(d + ((size_t)(bh*4096 + m) << 7) + col) = o;
}

// past_v [16][3072][128] f32 -> v_t [16][128][4096] bf16 (cols 0..3071), transposed
__global__ void __launch_bounds__(256) k_cvt_past_vt(const float* __restrict__ s, u16* __restrict__ v_t){
  __shared__ u16 T[64][65];
  const int mt = blockIdx.x, dt = blockIdx.y, pl = blockIdx.z;
  const float* src = s + (size_t)pl*3072*128 + (size_t)mt*64*128 + dt*64;
  u16* dst = v_t + (size_t)pl*128*4096 + (size_t)dt*64*4096 + mt*64;
  const int t = threadIdx.x;
  #pragma unroll
  for (int r = 0; r < 2; ++r){
    int row = r*32 + (t >> 3);
    int c8 = (t & 7)*8;
    float4 va = *(const float4*)(src + (size_t)row*128 + c8);
    float4 vb = *(const float4*)(src + (size_t)row*128 + c8 + 4);
    T[row][c8+0]=f2bf(va.x); T[row][c8+1]=f2bf(va.y); T[row][c8+2]=f2bf(va.z); T[row][c8+3]=f2bf(va.w);
    T[row][c8+4]=f2bf(vb.x); T[row][c8+5]=f2bf(vb.y); T[row][c8+6]=f2bf(vb.z); T[row][c8+7]=f2bf(vb.w);
  }
  __syncthreads();
  #pragma unroll
  for (int r = 0; r < 2; ++r){
    int drow = r*32 + (t >> 3);
    int m8 = (t & 7)*8;
    union { bfrag v; u16 e[8]; } uv;
    #pragma unroll
    for (int j = 0; j < 8; ++j) uv.e[j] = T[m8 + j][drow];
    *(bfrag*)(dst + (size_t)drow*4096 + m8) = uv.v;
  }
}

// ---------------- GEMM C[M][N] = A[M][K] * B[N][K]^T ----------------
template<int EPI>
__global__ void __launch_bounds__(256) k_gemm(
    const u16* __restrict__ A, const u16* __restrict__ Bm,
    u16* __restrict__ Cb, float* __restrict__ Cf, const float* __restrict__ bias,
    int M, int Nn, int K)
{
  __shared__ u16 lsA[2][4096];
  __shared__ u16 lsB[2][4096];
  const int t = threadIdx.x, lane = t & 63, wid = t >> 6;
  const int l15 = lane & 15, l4 = lane >> 4;
  const int wm = wid >> 1, wn = wid & 1;
  const int bn = blockIdx.x, bm = blockIdx.y;
  const u16* Ab = A + (size_t)bm*128*K;
  const u16* Bb = Bm + (size_t)bn*128*K;

  auto stage = [&](u16* ls, const u16* g, int kof){
    #pragma unroll
    for (int r = 0; r < 2; ++r){
      int row = r*64 + (t >> 2);
      int s = (t & 3) ^ ((row >> 1) & 3);
      gload_lds16(g + (size_t)row*K + kof + s*8, ls + r*2048 + wid*512);
    }
  };

  f32x4 acc[4][4] = {};
  stage(&lsA[0][0], Ab, 0);
  stage(&lsB[0][0], Bb, 0);
  const int NT = K >> 5;
  const int sl = l4 ^ ((l15 >> 1) & 3);
  const int ra0 = wm*64 + l15, rb0 = wn*64 + l15;
  for (int kt = 0; kt < NT; ++kt){
    __syncthreads();
    const int cur = kt & 1;
    if (kt + 1 < NT){
      stage(&lsA[cur ^ 1][0], Ab, (kt + 1)*32);
      stage(&lsB[cur ^ 1][0], Bb, (kt + 1)*32);
    }
    bfrag af[4], bfv[4];
    #pragma unroll
    for (int i = 0; i < 4; ++i){
      af[i]  = *(const bfrag*)&lsA[cur][(ra0 + i*16)*32 + sl*8];
      bfv[i] = *(const bfrag*)&lsB[cur][(rb0 + i*16)*32 + sl*8];
    }
    #pragma unroll
    for (int i = 0; i < 4; ++i)
      #pragma unroll
      for (int j = 0; j < 4; ++j)
        acc[i][j] = __builtin_amdgcn_mfma_f32_16x16x32_bf16(af[i], bfv[j], acc[i][j], 0, 0, 0);
  }
  const int row0 = bm*128 + wm*64, col0 = bn*128 + wn*64;
  #pragma unroll
  for (int i = 0; i < 4; ++i)
    #pragma unroll
    for (int j = 0; j < 4; ++j){
      int cc = col0 + j*16 + l15;
      float bv = (EPI == 1) ? bias[cc] : 0.f;
      #pragma unroll
      for (int r = 0; r < 4; ++r){
        int rr = row0 + i*16 + l4*4 + r;
        if (EPI == 0) Cb[(size_t)rr*Nn + cc] = f2bf(acc[i][j][r]);
        else          Cf[(size_t)rr*Nn + cc] = acc[i][j][r] + bv;
      }
    }
}

// ---------------- fused RMSNorm + RoPE + scatter (q pre-scaled by log2e/sqrt(D)) ----------------
__global__ void __launch_bounds__(256) k_rmsrope(
    const u16* __restrict__ proj, const float* __restrict__ cosb, const float* __restrict__ sinb,
    const float* __restrict__ wq, const float* __restrict__ wk,
    u16* __restrict__ q_ro, u16* __restrict__ k_all, u16* __restrict__ v_all)
{
  const int bn = blockIdx.x;
  const int b = bn >> 10, n = bn & 1023;
  const int lane = threadIdx.x & 63, w = threadIdx.x >> 6;
  const int chunk = blockIdx.y*4 + w;
  const u16* src = proj + (size_t)bn*3072 + chunk*128 + lane*2;
  const u32 raw = *(const u32*)src;
  union { u32 u; float f; } a, c2;
  a.u = raw << 16; c2.u = raw & 0xffff0000u;
  float x0 = a.f, x1 = c2.f;
  if (chunk >= 20){
    int hk = chunk - 20;
    *(u32*)(v_all + (((size_t)(b*4 + hk)*4096 + 3072 + n) << 7) + lane*2) = raw;
    return;
  }
  float ss = x0*x0 + x1*x1;
  #pragma unroll
  for (int m = 1; m < 64; m <<= 1) ss += __shfl_xor(ss, m, 64);
  float inv = rsqrtf(ss*(1.f/128.f) + 1e-6f);
  const float* wn2 = (chunk < 16) ? wq : wk;
  x0 *= inv*wn2[lane*2]; x1 *= inv*wn2[lane*2 + 1];
  float cz = cosb[n*64 + lane], sz = sinb[n*64 + lane];
  float r0 = x0*cz - x1*sz;
  float r1 = x0*sz + x1*cz;
  if (chunk < 16){
    const float KLF = 0.127529904f;   // log2(e)/sqrt(128) folded into q
    r0 *= KLF; r1 *= KLF;
    u32 outp = (u32)f2bf(r0) | ((u32)f2bf(r1) << 16);
    *(u32*)(q_ro + (((size_t)(b*16 + chunk)*1024 + n) << 7) + lane*2) = outp;
  } else {
    int hk = chunk - 16;
    u32 outp = (u32)f2bf(r0) | ((u32)f2bf(r1) << 16);
    *(u32*)(k_all + (((size_t)(b*4 + hk)*4096 + 3072 + n) << 7) + lane*2) = outp;
  }
}

// ---------------- V transpose (new rows only): v_all[pl][m][d] -> v_t[pl][d][m] ----------------
__global__ void __launch_bounds__(256) k_transpose_v(const u16* __restrict__ v_all, u16* __restrict__ v_t){
  __shared__ u16 T[64][65];
  const int mt = blockIdx.x + 48, dt = blockIdx.y, pl = blockIdx.z;
  const u16* src = v_all + (size_t)pl*4096*128 + (size_t)mt*64*128 + dt*64;
  u16* dst = v_t + (size_t)pl*128*4096 + (size_t)dt*64*4096 + mt*64;
  const int t = threadIdx.x;
  #pragma unroll
  for (int r = 0; r < 2; ++r){
    int row = r*32 + (t >> 3);
    int c8 = (t & 7)*8;
    bfrag v = *(const bfrag*)(src + (size_t)row*128 + c8);
    union { bfrag v; u16 e[8]; } uv; uv.v = v;
    #pragma unroll
    for (int j = 0; j < 8; ++j) T[row][c8 + j] = uv.e[j];
  }
  __syncthreads();
  #pragma unroll
  for (int r = 0; r < 2; ++r){
    int drow = r*32 + (t >> 3);
    int m8 = (t & 7)*8;
    union { bfrag v; u16 e[8]; } uv;
    #pragma unroll
    for (int j = 0; j < 8; ++j) uv.e[j] = T[m8 + j][drow];
    *(bfrag*)(dst + (size_t)drow*4096 + m8) = uv.v;
  }
}

// ---------------- flash attention: LDS-free, register-pipelined K/V, no-max softmax ----------------
// grid 512: (b,hk,qt32); 8 waves = 4 heads x 2 k-halves; no barriers in main loop.
// kf/vf MFMA A-fragments loaded straight from global (per-lane 16B), L1/L2 serve reuse.
__global__ void __launch_bounds__(512, 2) k_attn(
    const u16* __restrict__ q_ro, const u16* __restrict__ k_all,
    const u16* __restrict__ v_t, u16* __restrict__ attn_o)
{
  __shared__ float Om[4][4096];    // 64 KB merge buffer (epilogue only)
  __shared__ float Lsh[4][32];
  const int bid = blockIdx.x;
  const int xcd = bid & 7, idx = bid >> 3;
  const int plane = (xcd << 1) | (idx >> 5);
  const int qt = idx & 31;
  const int b = plane >> 2, hk = plane & 3;
  const int t = threadIdx.x, lane = t & 63, w = t >> 6;
  const int l31 = lane & 31, lh = lane >> 5;
  const int hf = w >> 2;           // k-half of chunk
  const int hd = w & 3;            // head within group
  const int h = hk*4 + hd;
  const int qbase = qt*32;

  const u16* qplane = q_ro + (size_t)(b*16 + h)*1024*128;
  const u16* kplane = k_all + (size_t)(b*4 + hk)*4096*128;
  const u16* vplane = v_t  + (size_t)(b*4 + hk)*128*4096;

  // Q B-frags: lane holds Q[qbase+l31][dks*16 + lh*8 + j]
  bfrag qf[8];
  {
    const u16* qrow = qplane + (size_t)(qbase + l31)*128 + lh*8;
    #pragma unroll
    for (int dks = 0; dks < 8; ++dks)
      qf[dks] = *(const bfrag*)(qrow + dks*16);
  }

  const int kb0 = (qbase + 1024) & ~63;
  const int qpos = 3072 + qbase + l31;

  // lane-constant element offsets
  const u16* kbase0 = kplane + (hf*32 + l31)*128 + lh*8;          // + kb*128 + dks*16
  const u16* vbase0 = vplane + (size_t)l31*4096 + hf*32 + lh*8;   // + kb + dj*131072 + lks*16

  f32x16 acc_o[4] = {};
  float l_run = 0.f;

  bfrag kf[8], vf[8];
  // prologue loads for chunk 0
  {
    const u16* kb_p = kbase0 + (size_t)kb0*128;
    #pragma unroll
    for (int dks = 0; dks < 8; ++dks) kf[dks] = *(const bfrag*)(kb_p + dks*16);
    const u16* vb_p = vbase0 + kb0;
    #pragma unroll
    for (int lks = 0; lks < 2; ++lks)
      #pragma unroll
      for (int dj = 0; dj < 4; ++dj)
        vf[lks*4 + dj] = *(const bfrag*)(vb_p + (size_t)dj*131072 + lks*16);
  }

  for (int c = 0; c < 33; ++c){
    const int kb = kb0 + c*64;

    // S^T[k_local][q] = K_half · Q^T  (KL scale pre-folded into Q)
    f32x16 s = {};
    __builtin_amdgcn_s_setprio(1);
    #pragma unroll
    for (int dks = 0; dks < 8; ++dks)
      s = __builtin_amdgcn_mfma_f32_32x32x16_bf16(kf[dks], qf[dks], s, 0, 0, 0);
    __builtin_amdgcn_s_setprio(0);

    // refill kf for next chunk (lands during softmax+PV)
    if (c < 32){
      const u16* kb_n = kbase0 + (size_t)(kb + 64)*128;
      #pragma unroll
      for (int dks = 0; dks < 8; ++dks) kf[dks] = *(const bfrag*)(kb_n + dks*16);
    }

    if ((c == 0) | (c == 32)){
      #pragma unroll
      for (int r = 0; r < 16; ++r){
        int kpos = kb + hf*32 + (r & 3) + 8*(r >> 2) + 4*lh;
        int dq = qpos - kpos;
        if ((unsigned)dq >= 2048u) s[r] = -1e30f;
      }
    }

    // p = exp2(s); l += sum(p)  (no max tracking: |s_raw*KL| <= 16.3)
    #pragma unroll
    for (int r = 0; r < 16; ++r) s[r] = exp2f(s[r]);
    {
      float a0 = (s[0]+s[1]) + (s[2]+s[3]);
      float a1 = (s[4]+s[5]) + (s[6]+s[7]);
      float a2 = (s[8]+s[9]) + (s[10]+s[11]);
      float a3 = (s[12]+s[13]) + (s[14]+s[15]);
      float lc = (a0 + a1) + (a2 + a3);
      lc += __shfl_xor(lc, 32, 64);
      l_run += lc;
    }

    // P^T B-frags via cvt_pk + permlane32_swap
    union { u32 u[4]; bfrag v; } pf[2];
    {
      u32 a0 = cvtpk(s[0],  s[1]),  a1 = cvtpk(s[2],  s[3]);
      u32 b0 = cvtpk(s[4],  s[5]),  b1 = cvtpk(s[6],  s[7]);
      swap32(a0, b0); swap32(a1, b1);
      pf[0].u[0]=a0; pf[0].u[1]=a1; pf[0].u[2]=b0; pf[0].u[3]=b1;
      u32 c0 = cvtpk(s[8],  s[9]),  c1 = cvtpk(s[10], s[11]);
      u32 e0 = cvtpk(s[12], s[13]), e1 = cvtpk(s[14], s[15]);
      swap32(c0, e0); swap32(c1, e1);
      pf[1].u[0]=c0; pf[1].u[1]=c1; pf[1].u[2]=e0; pf[1].u[3]=e1;
    }

    // O^T[d][q] += V^T · P^T  (our k columns: ks = hf*2 + lks)
    __builtin_amdgcn_s_setprio(1);
    #pragma unroll
    for (int lks = 0; lks < 2; ++lks)
      #pragma unroll
      for (int dj = 0; dj < 4; ++dj)
        acc_o[dj] = __builtin_amdgcn_mfma_f32_32x32x16_bf16(vf[lks*4 + dj], pf[lks].v, acc_o[dj], 0, 0, 0);
    __builtin_amdgcn_s_setprio(0);

    // refill vf for next chunk (lands during next QK+softmax)
    if (c < 32){
      const u16* vb_n = vbase0 + kb + 64;
      #pragma unroll
      for (int lks = 0; lks < 2; ++lks)
        #pragma unroll
        for (int dj = 0; dj < 4; ++dj)
          vf[lks*4 + dj] = *(const bfrag*)(vb_n + (size_t)dj*131072 + lks*16);
    }
  }

  // ---- merge k-halves through LDS ----
  __syncthreads();
  if (hf == 1){
    if (lh == 0) Lsh[hd][l31] = l_run;
    #pragma unroll
    for (int dj = 0; dj < 4; ++dj)
      #pragma unroll
      for (int rg = 0; rg < 4; ++rg){
        int slot = dj*8 + rg*2 + lh;
        f32x4 vv;
        #pragma unroll
        for (int j = 0; j < 4; ++j) vv[j] = acc_o[dj][rg*4 + j];
        *(f32x4*)&Om[hd][l31*128 + ((slot ^ (l31 & 7)) << 2)] = vv;
      }
  }
  __syncthreads();
  if (hf == 0){
    float ltot = l_run + Lsh[hd][l31];
    float inv = 1.0f / ltot;
    const int bn = b*1024 + qbase + l31;
    u16* orow = attn_o + (size_t)bn*2048 + h*128;
    #pragma unroll
    for (int dj = 0; dj < 4; ++dj)
      #pragma unroll
      for (int rg = 0; rg < 4; ++rg){
        int slot = dj*8 + rg*2 + lh;
        f32x4 vv = *(const f32x4*)&Om[hd][l31*128 + ((slot ^ (l31 & 7)) << 2)];
        int d0 = dj*32 + rg*8 + lh*4;
        u16x4 o;
        #pragma unroll
        for (int j = 0; j < 4; ++j) o[j] = f2bf((acc_o[dj][rg*4 + j] + vv[j])*inv);
        *(u16x4*)(orow + d0) = o;
      }
  }
}

// ---------------- launch ----------------
extern "C" void kernel_launch(void* const* d_in, const int* in_sizes, int n_in,
                              void* d_out, int out_size, void* d_ws, size_t ws_size,
                              hipStream_t stream)
{
  const float* x      = (const float*)d_in[0];
  const float* past_k = (const float*)d_in[1];
  const float* past_v = (const float*)d_in[2];
  const float* fcos   = (const float*)d_in[3];
  const float* fsin   = (const float*)d_in[4];
  const float* Wq     = (const float*)d_in[5];
  const float* Wk     = (const float*)d_in[6];
  const float* Wv     = (const float*)d_in[7];
  const float* Wo     = (const float*)d_in[8];
  const float* bo     = (const float*)d_in[9];
  const float* wqn    = (const float*)d_in[10];
  const float* wkn    = (const float*)d_in[11];
  float* out = (float*)d_out;
  char* ws = (char*)d_ws;

  u16* xb    = (u16*)(ws);
  u16* wqkv  = (u16*)(ws + 16777216);
  u16* wo_b  = (u16*)(ws + 29360128);
  u16* q_ro  = (u16*)(ws + 37748736);
  u16* k_all = (u16*)(ws + 54525952);
  u16* v_all = (u16*)(ws + 71303168);
  u16* v_t   = (u16*)(ws + 88080384);
  u16* proj  = (u16*)(ws + 104857600);
  u16* attn_o = proj;

  k_cvt<<<8192, 256, 0, stream>>>(x, xb, 2097152);
  k_cvt<<<4096, 256, 0, stream>>>(Wq, wqkv, 1048576);
  k_cvt<<<1024, 256, 0, stream>>>(Wk, wqkv + 2048*2048, 262144);
  k_cvt<<<1024, 256, 0, stream>>>(Wv, wqkv + 2560*2048, 262144);
  k_cvt<<<4096, 256, 0, stream>>>(Wo, wo_b, 1048576);
  k_cvt_past<<<6144, 256, 0, stream>>>(past_k, k_all, 1572864);
  k_cvt_past_vt<<<dim3(48, 2, 16), 256, 0, stream>>>(past_v, v_t);

  k_gemm<0><<<dim3(24, 32), 256, 0, stream>>>(xb, wqkv, proj, nullptr, nullptr, 4096, 3072, 2048);
  k_rmsrope<<<dim3(4096, 6), 256, 0, stream>>>(proj, fcos, fsin, wqn, wkn, q_ro, k_all, v_all);
  k_transpose_v<<<dim3(16, 2, 16), 256, 0, stream>>>(v_all, v_t);
  k_attn<<<512, 512, 0, stream>>>(q_ro, k_all, v_t, attn_o);
  k_gemm<1><<<dim3(16, 32), 256, 0, stream>>>(attn_o, wo_b, nullptr, out, bo, 4096, 2048, 2048);
}

// Round 6
// 264.303 us; speedup vs baseline: 1.5206x; 1.5206x over previous
//
#include <hip/hip_runtime.h>
#include <hip/hip_bf16.h>
#include <stdint.h>

typedef unsigned short u16;
typedef unsigned int u32;
typedef __attribute__((ext_vector_type(8))) __bf16 bfrag;
typedef __attribute__((ext_vector_type(4))) float f32x4;
typedef __attribute__((ext_vector_type(16))) float f32x16;
typedef __attribute__((ext_vector_type(4))) unsigned short u16x4;

__device__ __forceinline__ u16 f2bf(float f){
  union { float f; u32 u; } v; v.f = f;
  u32 u = v.u;
  return (u16)((u + 0x7fffu + ((u >> 16) & 1u)) >> 16);
}

__device__ __forceinline__ u32 cvtpk(float a, float b){
  u32 r; asm("v_cvt_pk_bf16_f32 %0, %1, %2" : "=v"(r) : "v"(a), "v"(b)); return r;
}
__device__ __forceinline__ void swap32(u32 &a, u32 &b){
  asm volatile("v_permlane32_swap_b32 %0, %1" : "+v"(a), "+v"(b));
}

__device__ __forceinline__ void gload_lds16(const void* g, void* l){
  __builtin_amdgcn_global_load_lds(
      (__attribute__((address_space(1))) void*)(unsigned long long)g,
      (__attribute__((address_space(3))) void*)(u32)(unsigned long long)l,
      16, 0, 0);
}

// ---------------- converts ----------------
__global__ void __launch_bounds__(256) k_cvt(const float* __restrict__ s, u16* __restrict__ d, int n4){
  int i = blockIdx.x*256 + threadIdx.x;
  if (i >= n4) return;
  float4 v = ((const float4*)s)[i];
  u16x4 o; o[0]=f2bf(v.x); o[1]=f2bf(v.y); o[2]=f2bf(v.z); o[3]=f2bf(v.w);
  ((u16x4*)d)[i] = o;
}

// past_k f32 [pl][3072][128] -> Kr fragment layout, kc 16..47
// Kr elem: [pl][kc<64][fhi=hf*8+dks][lane64][8]  (frag = K[kc*64+hf*32+(lane&31)][dks*16+(lane>>5)*8 + j])
__global__ void __launch_bounds__(256) k_past_kr(const float* __restrict__ pk, u16* __restrict__ Kr){
  __shared__ u16 TK[64][128];
  const int kc = 16 + blockIdx.x;
  const int pl = blockIdx.y;
  const int t = threadIdx.x;
  const float* src = pk + (size_t)pl*393216 + (size_t)kc*8192;
  #pragma unroll
  for (int i = 0; i < 8; ++i){
    int e = i*1024 + t*4;
    float4 v = *(const float4*)(src + e);
    u16x4 o; o[0]=f2bf(v.x); o[1]=f2bf(v.y); o[2]=f2bf(v.z); o[3]=f2bf(v.w);
    *(u16x4*)&TK[e>>7][e&127] = o;
  }
  __syncthreads();
  u16* dst = Kr + (size_t)pl*524288 + (size_t)kc*8192;
  #pragma unroll
  for (int i = 0; i < 4; ++i){
    int f = i*256 + t;
    int fhi = f >> 6, lf = f & 63;
    int row = ((f >> 9) << 5) | (lf & 31);           // hf*32 + l31
    int col = ((fhi & 7) << 4) | ((lf >> 5) << 3);   // dks*16 + lh*8
    bfrag v = *(const bfrag*)&TK[row][col];
    *(bfrag*)(dst + fhi*512 + lf*8) = v;
  }
}

// past_v f32 [pl][3072][128] -> Vr fragment layout, kc 16..47
// Vr elem: [pl][kc][ghi=hf*8+lks*4+dj][lane64][8] (frag = V[kc*64+hf*32+lks*16+(lane>>5)*8+j][dj*32+(lane&31)])
__global__ void __launch_bounds__(256) k_past_vr(const float* __restrict__ pv, u16* __restrict__ Vr){
  __shared__ u16 T2[128][80];
  const int kc = 16 + blockIdx.x;
  const int pl = blockIdx.y;
  const int t = threadIdx.x;
  const float* src = pv + (size_t)pl*393216 + (size_t)kc*8192;
  #pragma unroll
  for (int i = 0; i < 8; ++i){
    int e = i*1024 + t*4;
    int row = e >> 7, d0 = e & 127;
    float4 v = *(const float4*)(src + e);
    T2[d0][row]   = f2bf(v.x);
    T2[d0+1][row] = f2bf(v.y);
    T2[d0+2][row] = f2bf(v.z);
    T2[d0+3][row] = f2bf(v.w);
  }
  __syncthreads();
  u16* dst = Vr + (size_t)pl*524288 + (size_t)kc*8192;
  #pragma unroll
  for (int i = 0; i < 4; ++i){
    int g = i*256 + t;
    int ghi = g >> 6, lg = g & 63;
    int d  = ((ghi & 3) << 5) | (lg & 31);                            // dj*32 + l31
    int k0 = ((g >> 9) << 5) | (((ghi >> 2) & 1) << 4) | ((lg >> 5) << 3); // hf*32+lks*16+lh*8
    bfrag v = *(const bfrag*)&T2[d][k0];
    *(bfrag*)(dst + ghi*512 + lg*8) = v;
  }
}

// v_new bf16 [pl][1024][128] -> Vr, kc 48..63
__global__ void __launch_bounds__(256) k_new_vr(const u16* __restrict__ vn, u16* __restrict__ Vr){
  __shared__ u16 T2[128][80];
  const int kcl = blockIdx.x;   // 0..15
  const int pl = blockIdx.y;
  const int t = threadIdx.x;
  const u16* src = vn + (size_t)pl*131072 + (size_t)kcl*8192;
  #pragma unroll
  for (int i = 0; i < 4; ++i){
    int e = i*2048 + t*8;
    int row = e >> 7, d0 = e & 127;
    union { bfrag v; u16 x[8]; } u;
    u.v = *(const bfrag*)(src + e);
    #pragma unroll
    for (int j = 0; j < 8; ++j) T2[d0+j][row] = u.x[j];
  }
  __syncthreads();
  u16* dst = Vr + (size_t)pl*524288 + (size_t)(48 + kcl)*8192;
  #pragma unroll
  for (int i = 0; i < 4; ++i){
    int g = i*256 + t;
    int ghi = g >> 6, lg = g & 63;
    int d  = ((ghi & 3) << 5) | (lg & 31);
    int k0 = ((g >> 9) << 5) | (((ghi >> 2) & 1) << 4) | ((lg >> 5) << 3);
    bfrag v = *(const bfrag*)&T2[d][k0];
    *(bfrag*)(dst + ghi*512 + lg*8) = v;
  }
}

// ---------------- GEMM C[M][N] = A[M][K] * B[N][K]^T ----------------
template<int EPI>
__global__ void __launch_bounds__(256) k_gemm(
    const u16* __restrict__ A, const u16* __restrict__ Bm,
    u16* __restrict__ Cb, float* __restrict__ Cf, const float* __restrict__ bias,
    int M, int Nn, int K)
{
  __shared__ u16 lsA[2][4096];
  __shared__ u16 lsB[2][4096];
  const int t = threadIdx.x, lane = t & 63, wid = t >> 6;
  const int l15 = lane & 15, l4 = lane >> 4;
  const int wm = wid >> 1, wn = wid & 1;
  const int bn = blockIdx.x, bm = blockIdx.y;
  const u16* Ab = A + (size_t)bm*128*K;
  const u16* Bb = Bm + (size_t)bn*128*K;

  auto stage = [&](u16* ls, const u16* g, int kof){
    #pragma unroll
    for (int r = 0; r < 2; ++r){
      int row = r*64 + (t >> 2);
      int s = (t & 3) ^ ((row >> 1) & 3);
      gload_lds16(g + (size_t)row*K + kof + s*8, ls + r*2048 + wid*512);
    }
  };

  f32x4 acc[4][4] = {};
  stage(&lsA[0][0], Ab, 0);
  stage(&lsB[0][0], Bb, 0);
  const int NT = K >> 5;
  const int sl = l4 ^ ((l15 >> 1) & 3);
  const int ra0 = wm*64 + l15, rb0 = wn*64 + l15;
  for (int kt = 0; kt < NT; ++kt){
    __syncthreads();
    const int cur = kt & 1;
    if (kt + 1 < NT){
      stage(&lsA[cur ^ 1][0], Ab, (kt + 1)*32);
      stage(&lsB[cur ^ 1][0], Bb, (kt + 1)*32);
    }
    bfrag af[4], bfv[4];
    #pragma unroll
    for (int i = 0; i < 4; ++i){
      af[i]  = *(const bfrag*)&lsA[cur][(ra0 + i*16)*32 + sl*8];
      bfv[i] = *(const bfrag*)&lsB[cur][(rb0 + i*16)*32 + sl*8];
    }
    #pragma unroll
    for (int i = 0; i < 4; ++i)
      #pragma unroll
      for (int j = 0; j < 4; ++j)
        acc[i][j] = __builtin_amdgcn_mfma_f32_16x16x32_bf16(af[i], bfv[j], acc[i][j], 0, 0, 0);
  }
  const int row0 = bm*128 + wm*64, col0 = bn*128 + wn*64;
  #pragma unroll
  for (int i = 0; i < 4; ++i)
    #pragma unroll
    for (int j = 0; j < 4; ++j){
      int cc = col0 + j*16 + l15;
      float bv = (EPI == 1) ? bias[cc] : 0.f;
      #pragma unroll
      for (int r = 0; r < 4; ++r){
        int rr = row0 + i*16 + l4*4 + r;
        if (EPI == 0) Cb[(size_t)rr*Nn + cc] = f2bf(acc[i][j][r]);
        else          Cf[(size_t)rr*Nn + cc] = acc[i][j][r] + bv;
      }
    }
}

// ---------------- fused RMSNorm + RoPE + scatter ----------------
// q: row-major q_ro (pre-scaled by log2e/sqrt(D)); k: scattered into Kr frags; v: rows into v_new
__global__ void __launch_bounds__(256) k_rmsrope(
    const u16* __restrict__ proj, const float* __restrict__ cosb, const float* __restrict__ sinb,
    const float* __restrict__ wq, const float* __restrict__ wk,
    u16* __restrict__ q_ro, u16* __restrict__ Kr, u16* __restrict__ v_new)
{
  const int bn = blockIdx.x;
  const int b = bn >> 10, n = bn & 1023;
  const int lane = threadIdx.x & 63, w = threadIdx.x >> 6;
  const int chunk = blockIdx.y*4 + w;
  const u16* src = proj + (size_t)bn*3072 + chunk*128 + lane*2;
  const u32 raw = *(const u32*)src;
  union { u32 u; float f; } a, c2;
  a.u = raw << 16; c2.u = raw & 0xffff0000u;
  float x0 = a.f, x1 = c2.f;
  if (chunk >= 20){
    int hk = chunk - 20;
    *(u32*)(v_new + ((size_t)(b*4 + hk)*1024 + n)*128 + lane*2) = raw;
    return;
  }
  float ss = x0*x0 + x1*x1;
  #pragma unroll
  for (int m = 1; m < 64; m <<= 1) ss += __shfl_xor(ss, m, 64);
  float inv = rsqrtf(ss*(1.f/128.f) + 1e-6f);
  const float* wn2 = (chunk < 16) ? wq : wk;
  x0 *= inv*wn2[lane*2]; x1 *= inv*wn2[lane*2 + 1];
  float cz = cosb[n*64 + lane], sz = sinb[n*64 + lane];
  float r0 = x0*cz - x1*sz;
  float r1 = x0*sz + x1*cz;
  if (chunk < 16){
    const float KLF = 0.127529904f;   // log2(e)/sqrt(128) folded into q
    r0 *= KLF; r1 *= KLF;
    u32 outp = (u32)f2bf(r0) | ((u32)f2bf(r1) << 16);
    *(u32*)(q_ro + (((size_t)(b*16 + chunk)*1024 + n) << 7) + lane*2) = outp;
  } else {
    int hk = chunk - 16;
    u32 outp = (u32)f2bf(r0) | ((u32)f2bf(r1) << 16);
    int kpos = 3072 + n;
    // Kr frag coords: d = 2*lane -> dks=lane>>3, lh=(lane>>2)&1, j=(2*lane)&7
    size_t idx = (size_t)(b*4 + hk)*524288
               + (size_t)(((kpos >> 6)*16) + (((kpos >> 5) & 1)*8) + (lane >> 3))*512
               + (size_t)((((lane >> 2) & 1) << 5) | (kpos & 31))*8
               + ((2*lane) & 7);
    *(u32*)(Kr + idx) = outp;
  }
}

// ---------------- flash attention: LDS-free, fragment-ordered global K/V ----------------
// grid 512: (b,hk,qt32); 8 waves = 4 heads x 2 k-halves; no barriers in main loop.
__global__ void __launch_bounds__(512, 2) k_attn(
    const u16* __restrict__ q_ro, const u16* __restrict__ Kr,
    const u16* __restrict__ Vr, u16* __restrict__ attn_o)
{
  __shared__ float Om[4][4096];    // merge buffer (epilogue only)
  __shared__ float Lsh[4][32];
  const int bid = blockIdx.x;
  const int xcd = bid & 7, idx = bid >> 3;
  const int plane = (xcd << 1) | (idx >> 5);
  const int qt = idx & 31;
  const int b = plane >> 2, hk = plane & 3;
  const int t = threadIdx.x, lane = t & 63, w = t >> 6;
  const int l31 = lane & 31, lh = lane >> 5;
  const int hf = w >> 2;           // k-half of chunk
  const int hd = w & 3;            // head within group
  const int h = hk*4 + hd;
  const int qbase = qt*32;

  const u16* qplane = q_ro + (size_t)(b*16 + h)*1024*128;
  const u16* kplane = Kr + (size_t)(b*4 + hk)*524288;
  const u16* vplane = Vr + (size_t)(b*4 + hk)*524288;

  // Q B-frags: lane holds Q[qbase+l31][dks*16 + lh*8 + j]
  bfrag qf[8];
  {
    const u16* qrow = qplane + (size_t)(qbase + l31)*128 + lh*8;
    #pragma unroll
    for (int dks = 0; dks < 8; ++dks)
      qf[dks] = *(const bfrag*)(qrow + dks*16);
  }

  const int kb0 = (qbase + 1024) & ~63;
  const int kc0 = kb0 >> 6;
  const int qpos = 3072 + qbase + l31;

  // coalesced fragment bases (include hf and lane)
  const u16* kfb = kplane + (size_t)hf*4096 + (size_t)lane*8;   // + kc*8192 + dks*512
  const u16* vfb = vplane + (size_t)hf*4096 + (size_t)lane*8;   // + kc*8192 + (lks*4+dj)*512

  f32x16 acc_o[4] = {};
  float l_run = 0.f;

  bfrag kf[8], vf[8];
  {
    const u16* kp = kfb + (size_t)kc0*8192;
    #pragma unroll
    for (int dks = 0; dks < 8; ++dks) kf[dks] = *(const bfrag*)(kp + dks*512);
    #pragma unroll
    for (int q8 = 0; q8 < 8; ++q8) vf[q8] = *(const bfrag*)(kp + 4096 + q8*512); // vfb same plane offset? no:
  }
  // (fix) proper vf prologue:
  {
    const u16* vp = vfb + (size_t)kc0*8192;
    #pragma unroll
    for (int q8 = 0; q8 < 8; ++q8) vf[q8] = *(const bfrag*)(vp + q8*512);
  }

  for (int c = 0; c < 33; ++c){
    const int kb = kb0 + c*64;

    // S^T[k_local][q] = K_half · Q^T  (KL scale pre-folded into Q)
    f32x16 s = {};
    __builtin_amdgcn_s_setprio(1);
    #pragma unroll
    for (int dks = 0; dks < 8; ++dks)
      s = __builtin_amdgcn_mfma_f32_32x32x16_bf16(kf[dks], qf[dks], s, 0, 0, 0);
    __builtin_amdgcn_s_setprio(0);

    // refill kf for next chunk (lands during softmax+PV)
    if (c < 32){
      const u16* kp = kfb + (size_t)(kc0 + c + 1)*8192;
      #pragma unroll
      for (int dks = 0; dks < 8; ++dks) kf[dks] = *(const bfrag*)(kp + dks*512);
    }

    if ((c == 0) | (c == 32)){
      #pragma unroll
      for (int r = 0; r < 16; ++r){
        int kpos = kb + hf*32 + (r & 3) + 8*(r >> 2) + 4*lh;
        int dq = qpos - kpos;
        if ((unsigned)dq >= 2048u) s[r] = -1e30f;
      }
    }

    // p = exp2(s); l += sum(p)  (no max tracking: |s_raw*KL| <= 16.3)
    #pragma unroll
    for (int r = 0; r < 16; ++r) s[r] = exp2f(s[r]);
    {
      float a0 = (s[0]+s[1]) + (s[2]+s[3]);
      float a1 = (s[4]+s[5]) + (s[6]+s[7]);
      float a2 = (s[8]+s[9]) + (s[10]+s[11]);
      float a3 = (s[12]+s[13]) + (s[14]+s[15]);
      float lc = (a0 + a1) + (a2 + a3);
      lc += __shfl_xor(lc, 32, 64);
      l_run += lc;
    }

    // P^T B-frags via cvt_pk + permlane32_swap
    union { u32 u[4]; bfrag v; } pf[2];
    {
      u32 a0 = cvtpk(s[0],  s[1]),  a1 = cvtpk(s[2],  s[3]);
      u32 b0 = cvtpk(s[4],  s[5]),  b1 = cvtpk(s[6],  s[7]);
      swap32(a0, b0); swap32(a1, b1);
      pf[0].u[0]=a0; pf[0].u[1]=a1; pf[0].u[2]=b0; pf[0].u[3]=b1;
      u32 c0 = cvtpk(s[8],  s[9]),  c1 = cvtpk(s[10], s[11]);
      u32 e0 = cvtpk(s[12], s[13]), e1 = cvtpk(s[14], s[15]);
      swap32(c0, e0); swap32(c1, e1);
      pf[1].u[0]=c0; pf[1].u[1]=c1; pf[1].u[2]=e0; pf[1].u[3]=e1;
    }

    // O^T[d][q] += V^T · P^T
    __builtin_amdgcn_s_setprio(1);
    #pragma unroll
    for (int lks = 0; lks < 2; ++lks)
      #pragma unroll
      for (int dj = 0; dj < 4; ++dj)
        acc_o[dj] = __builtin_amdgcn_mfma_f32_32x32x16_bf16(vf[lks*4 + dj], pf[lks].v, acc_o[dj], 0, 0, 0);
    __builtin_amdgcn_s_setprio(0);

    // refill vf for next chunk (lands during next QK+softmax)
    if (c < 32){
      const u16* vp = vfb + (size_t)(kc0 + c + 1)*8192;
      #pragma unroll
      for (int q8 = 0; q8 < 8; ++q8) vf[q8] = *(const bfrag*)(vp + q8*512);
    }
  }

  // ---- merge k-halves through LDS ----
  __syncthreads();
  if (hf == 1){
    if (lh == 0) Lsh[hd][l31] = l_run;
    #pragma unroll
    for (int dj = 0; dj < 4; ++dj)
      #pragma unroll
      for (int rg = 0; rg < 4; ++rg){
        int slot = dj*8 + rg*2 + lh;
        f32x4 vv;
        #pragma unroll
        for (int j = 0; j < 4; ++j) vv[j] = acc_o[dj][rg*4 + j];
        *(f32x4*)&Om[hd][l31*128 + ((slot ^ (l31 & 7)) << 2)] = vv;
      }
  }
  __syncthreads();
  if (hf == 0){
    float ltot = l_run + Lsh[hd][l31];
    float inv = 1.0f / ltot;
    const int bn = b*1024 + qbase + l31;
    u16* orow = attn_o + (size_t)bn*2048 + h*128;
    #pragma unroll
    for (int dj = 0; dj < 4; ++dj)
      #pragma unroll
      for (int rg = 0; rg < 4; ++rg){
        int slot = dj*8 + rg*2 + lh;
        f32x4 vv = *(const f32x4*)&Om[hd][l31*128 + ((slot ^ (l31 & 7)) << 2)];
        int d0 = dj*32 + rg*8 + lh*4;
        u16x4 o;
        #pragma unroll
        for (int j = 0; j < 4; ++j) o[j] = f2bf((acc_o[dj][rg*4 + j] + vv[j])*inv);
        *(u16x4*)(orow + d0) = o;
      }
  }
}

// ---------------- launch ----------------
extern "C" void kernel_launch(void* const* d_in, const int* in_sizes, int n_in,
                              void* d_out, int out_size, void* d_ws, size_t ws_size,
                              hipStream_t stream)
{
  const float* x      = (const float*)d_in[0];
  const float* past_k = (const float*)d_in[1];
  const float* past_v = (const float*)d_in[2];
  const float* fcos   = (const float*)d_in[3];
  const float* fsin   = (const float*)d_in[4];
  const float* Wq     = (const float*)d_in[5];
  const float* Wk     = (const float*)d_in[6];
  const float* Wv     = (const float*)d_in[7];
  const float* Wo     = (const float*)d_in[8];
  const float* bo     = (const float*)d_in[9];
  const float* wqn    = (const float*)d_in[10];
  const float* wkn    = (const float*)d_in[11];
  float* out = (float*)d_out;
  char* ws = (char*)d_ws;

  u16* xb    = (u16*)(ws);                 // 16.8 MB
  u16* wqkv  = (u16*)(ws + 16777216);      // 12.6 MB
  u16* wo_b  = (u16*)(ws + 29360128);      // 8.4 MB
  u16* q_ro  = (u16*)(ws + 37748736);      // 16.8 MB
  u16* Kr    = (u16*)(ws + 54525952);      // 16.8 MB
  u16* Vr    = (u16*)(ws + 71303168);      // 16.8 MB
  u16* v_new = (u16*)(ws + 88080384);      // 4.2 MB
  u16* proj  = (u16*)(ws + 92274688);      // 25.2 MB (attn_o aliases)
  u16* attn_o = proj;

  k_cvt<<<8192, 256, 0, stream>>>(x, xb, 2097152);
  k_cvt<<<4096, 256, 0, stream>>>(Wq, wqkv, 1048576);
  k_cvt<<<1024, 256, 0, stream>>>(Wk, wqkv + 2048*2048, 262144);
  k_cvt<<<1024, 256, 0, stream>>>(Wv, wqkv + 2560*2048, 262144);
  k_cvt<<<4096, 256, 0, stream>>>(Wo, wo_b, 1048576);
  k_past_kr<<<dim3(32, 16), 256, 0, stream>>>(past_k, Kr);
  k_past_vr<<<dim3(32, 16), 256, 0, stream>>>(past_v, Vr);

  k_gemm<0><<<dim3(24, 32), 256, 0, stream>>>(xb, wqkv, proj, nullptr, nullptr, 4096, 3072, 2048);
  k_rmsrope<<<dim3(4096, 6), 256, 0, stream>>>(proj, fcos, fsin, wqn, wkn, q_ro, Kr, v_new);
  k_new_vr<<<dim3(16, 16), 256, 0, stream>>>(v_new, Vr);
  k_attn<<<512, 512, 0, stream>>>(q_ro, Kr, Vr, attn_o);
  k_gemm<1><<<dim3(16, 32), 256, 0, stream>>>(attn_o, wo_b, nullptr, out, bo, 4096, 2048, 2048);
}

// Round 7
// 260.112 us; speedup vs baseline: 1.5451x; 1.0161x over previous
//
#include <hip/hip_runtime.h>
#include <hip/hip_bf16.h>
#include <stdint.h>

typedef unsigned short u16;
typedef unsigned int u32;
typedef __attribute__((ext_vector_type(8))) __bf16 bfrag;
typedef __attribute__((ext_vector_type(4))) float f32x4;
typedef __attribute__((ext_vector_type(16))) float f32x16;
typedef __attribute__((ext_vector_type(4))) unsigned short u16x4;

__device__ __forceinline__ u16 f2bf(float f){
  union { float f; u32 u; } v; v.f = f;
  u32 u = v.u;
  return (u16)((u + 0x7fffu + ((u >> 16) & 1u)) >> 16);
}

__device__ __forceinline__ u32 cvtpk(float a, float b){
  u32 r; asm("v_cvt_pk_bf16_f32 %0, %1, %2" : "=v"(r) : "v"(a), "v"(b)); return r;
}
__device__ __forceinline__ void swap32(u32 &a, u32 &b){
  asm volatile("v_permlane32_swap_b32 %0, %1" : "+v"(a), "+v"(b));
}

__device__ __forceinline__ void gload_lds16(const void* g, void* l){
  __builtin_amdgcn_global_load_lds(
      (__attribute__((address_space(1))) void*)(unsigned long long)g,
      (__attribute__((address_space(3))) void*)(u32)(unsigned long long)l,
      16, 0, 0);
}

// ---------------- converts ----------------
__global__ void __launch_bounds__(256) k_cvt(const float* __restrict__ s, u16* __restrict__ d, int n4){
  int i = blockIdx.x*256 + threadIdx.x;
  if (i >= n4) return;
  float4 v = ((const float4*)s)[i];
  u16x4 o; o[0]=f2bf(v.x); o[1]=f2bf(v.y); o[2]=f2bf(v.z); o[3]=f2bf(v.w);
  ((u16x4*)d)[i] = o;
}

// past_k f32 [pl][3072][128] -> Kr fragment layout, kc 16..47
// Kr elem: [pl][kc<64][fhi=hf*8+dks][lane64][8]  (frag = K[kc*64+hf*32+(lane&31)][dks*16+(lane>>5)*8 + j])
__global__ void __launch_bounds__(256) k_past_kr(const float* __restrict__ pk, u16* __restrict__ Kr){
  __shared__ u16 TK[64][128];
  const int kc = 16 + blockIdx.x;
  const int pl = blockIdx.y;
  const int t = threadIdx.x;
  const float* src = pk + (size_t)pl*393216 + (size_t)kc*8192;
  #pragma unroll
  for (int i = 0; i < 8; ++i){
    int e = i*1024 + t*4;
    float4 v = *(const float4*)(src + e);
    u16x4 o; o[0]=f2bf(v.x); o[1]=f2bf(v.y); o[2]=f2bf(v.z); o[3]=f2bf(v.w);
    *(u16x4*)&TK[e>>7][e&127] = o;
  }
  __syncthreads();
  u16* dst = Kr + (size_t)pl*524288 + (size_t)kc*8192;
  #pragma unroll
  for (int i = 0; i < 4; ++i){
    int f = i*256 + t;
    int fhi = f >> 6, lf = f & 63;
    int row = ((f >> 9) << 5) | (lf & 31);           // hf*32 + l31
    int col = ((fhi & 7) << 4) | ((lf >> 5) << 3);   // dks*16 + lh*8
    bfrag v = *(const bfrag*)&TK[row][col];
    *(bfrag*)(dst + fhi*512 + lf*8) = v;
  }
}

// past_v f32 [pl][3072][128] -> Vr fragment layout, kc 16..47
// Vr elem: [pl][kc][ghi=hf*8+lks*4+dj][lane64][8] (frag = V[kc*64+hf*32+lks*16+(lane>>5)*8+j][dj*32+(lane&31)])
__global__ void __launch_bounds__(256) k_past_vr(const float* __restrict__ pv, u16* __restrict__ Vr){
  __shared__ u16 T2[128][80];
  const int kc = 16 + blockIdx.x;
  const int pl = blockIdx.y;
  const int t = threadIdx.x;
  const float* src = pv + (size_t)pl*393216 + (size_t)kc*8192;
  #pragma unroll
  for (int i = 0; i < 8; ++i){
    int e = i*1024 + t*4;
    int row = e >> 7, d0 = e & 127;
    float4 v = *(const float4*)(src + e);
    T2[d0][row]   = f2bf(v.x);
    T2[d0+1][row] = f2bf(v.y);
    T2[d0+2][row] = f2bf(v.z);
    T2[d0+3][row] = f2bf(v.w);
  }
  __syncthreads();
  u16* dst = Vr + (size_t)pl*524288 + (size_t)kc*8192;
  #pragma unroll
  for (int i = 0; i < 4; ++i){
    int g = i*256 + t;
    int ghi = g >> 6, lg = g & 63;
    int d  = ((ghi & 3) << 5) | (lg & 31);                            // dj*32 + l31
    int k0 = ((g >> 9) << 5) | (((ghi >> 2) & 1) << 4) | ((lg >> 5) << 3); // hf*32+lks*16+lh*8
    bfrag v = *(const bfrag*)&T2[d][k0];
    *(bfrag*)(dst + ghi*512 + lg*8) = v;
  }
}

// v_new bf16 [pl][1024][128] -> Vr, kc 48..63
__global__ void __launch_bounds__(256) k_new_vr(const u16* __restrict__ vn, u16* __restrict__ Vr){
  __shared__ u16 T2[128][80];
  const int kcl = blockIdx.x;   // 0..15
  const int pl = blockIdx.y;
  const int t = threadIdx.x;
  const u16* src = vn + (size_t)pl*131072 + (size_t)kcl*8192;
  #pragma unroll
  for (int i = 0; i < 4; ++i){
    int e = i*2048 + t*8;
    int row = e >> 7, d0 = e & 127;
    union { bfrag v; u16 x[8]; } u;
    u.v = *(const bfrag*)(src + e);
    #pragma unroll
    for (int j = 0; j < 8; ++j) T2[d0+j][row] = u.x[j];
  }
  __syncthreads();
  u16* dst = Vr + (size_t)pl*524288 + (size_t)(48 + kcl)*8192;
  #pragma unroll
  for (int i = 0; i < 4; ++i){
    int g = i*256 + t;
    int ghi = g >> 6, lg = g & 63;
    int d  = ((ghi & 3) << 5) | (lg & 31);
    int k0 = ((g >> 9) << 5) | (((ghi >> 2) & 1) << 4) | ((lg >> 5) << 3);
    bfrag v = *(const bfrag*)&T2[d][k0];
    *(bfrag*)(dst + ghi*512 + lg*8) = v;
  }
}

// ---------------- GEMM C[M][N] = A[M][K] * B[N][K]^T ----------------
template<int EPI>
__global__ void __launch_bounds__(256) k_gemm(
    const u16* __restrict__ A, const u16* __restrict__ Bm,
    u16* __restrict__ Cb, float* __restrict__ Cf, const float* __restrict__ bias,
    int M, int Nn, int K)
{
  __shared__ u16 lsA[2][4096];
  __shared__ u16 lsB[2][4096];
  const int t = threadIdx.x, lane = t & 63, wid = t >> 6;
  const int l15 = lane & 15, l4 = lane >> 4;
  const int wm = wid >> 1, wn = wid & 1;
  const int bn = blockIdx.x, bm = blockIdx.y;
  const u16* Ab = A + (size_t)bm*128*K;
  const u16* Bb = Bm + (size_t)bn*128*K;

  auto stage = [&](u16* ls, const u16* g, int kof){
    #pragma unroll
    for (int r = 0; r < 2; ++r){
      int row = r*64 + (t >> 2);
      int s = (t & 3) ^ ((row >> 1) & 3);
      gload_lds16(g + (size_t)row*K + kof + s*8, ls + r*2048 + wid*512);
    }
  };

  f32x4 acc[4][4] = {};
  stage(&lsA[0][0], Ab, 0);
  stage(&lsB[0][0], Bb, 0);
  const int NT = K >> 5;
  const int sl = l4 ^ ((l15 >> 1) & 3);
  const int ra0 = wm*64 + l15, rb0 = wn*64 + l15;
  for (int kt = 0; kt < NT; ++kt){
    __syncthreads();
    const int cur = kt & 1;
    if (kt + 1 < NT){
      stage(&lsA[cur ^ 1][0], Ab, (kt + 1)*32);
      stage(&lsB[cur ^ 1][0], Bb, (kt + 1)*32);
    }
    bfrag af[4], bfv[4];
    #pragma unroll
    for (int i = 0; i < 4; ++i){
      af[i]  = *(const bfrag*)&lsA[cur][(ra0 + i*16)*32 + sl*8];
      bfv[i] = *(const bfrag*)&lsB[cur][(rb0 + i*16)*32 + sl*8];
    }
    #pragma unroll
    for (int i = 0; i < 4; ++i)
      #pragma unroll
      for (int j = 0; j < 4; ++j)
        acc[i][j] = __builtin_amdgcn_mfma_f32_16x16x32_bf16(af[i], bfv[j], acc[i][j], 0, 0, 0);
  }
  const int row0 = bm*128 + wm*64, col0 = bn*128 + wn*64;
  #pragma unroll
  for (int i = 0; i < 4; ++i)
    #pragma unroll
    for (int j = 0; j < 4; ++j){
      int cc = col0 + j*16 + l15;
      float bv = (EPI == 1) ? bias[cc] : 0.f;
      #pragma unroll
      for (int r = 0; r < 4; ++r){
        int rr = row0 + i*16 + l4*4 + r;
        if (EPI == 0) Cb[(size_t)rr*Nn + cc] = f2bf(acc[i][j][r]);
        else          Cf[(size_t)rr*Nn + cc] = acc[i][j][r] + bv;
      }
    }
}

// ---------------- fused RMSNorm + RoPE + scatter ----------------
// q: row-major q_ro (pre-scaled by log2e/sqrt(D)); k: scattered into Kr frags; v: rows into v_new
__global__ void __launch_bounds__(256) k_rmsrope(
    const u16* __restrict__ proj, const float* __restrict__ cosb, const float* __restrict__ sinb,
    const float* __restrict__ wq, const float* __restrict__ wk,
    u16* __restrict__ q_ro, u16* __restrict__ Kr, u16* __restrict__ v_new)
{
  const int bn = blockIdx.x;
  const int b = bn >> 10, n = bn & 1023;
  const int lane = threadIdx.x & 63, w = threadIdx.x >> 6;
  const int chunk = blockIdx.y*4 + w;
  const u16* src = proj + (size_t)bn*3072 + chunk*128 + lane*2;
  const u32 raw = *(const u32*)src;
  union { u32 u; float f; } a, c2;
  a.u = raw << 16; c2.u = raw & 0xffff0000u;
  float x0 = a.f, x1 = c2.f;
  if (chunk >= 20){
    int hk = chunk - 20;
    *(u32*)(v_new + ((size_t)(b*4 + hk)*1024 + n)*128 + lane*2) = raw;
    return;
  }
  float ss = x0*x0 + x1*x1;
  #pragma unroll
  for (int m = 1; m < 64; m <<= 1) ss += __shfl_xor(ss, m, 64);
  float inv = rsqrtf(ss*(1.f/128.f) + 1e-6f);
  const float* wn2 = (chunk < 16) ? wq : wk;
  x0 *= inv*wn2[lane*2]; x1 *= inv*wn2[lane*2 + 1];
  float cz = cosb[n*64 + lane], sz = sinb[n*64 + lane];
  float r0 = x0*cz - x1*sz;
  float r1 = x0*sz + x1*cz;
  if (chunk < 16){
    const float KLF = 0.127529904f;   // log2(e)/sqrt(128) folded into q
    r0 *= KLF; r1 *= KLF;
    u32 outp = (u32)f2bf(r0) | ((u32)f2bf(r1) << 16);
    *(u32*)(q_ro + (((size_t)(b*16 + chunk)*1024 + n) << 7) + lane*2) = outp;
  } else {
    int hk = chunk - 16;
    u32 outp = (u32)f2bf(r0) | ((u32)f2bf(r1) << 16);
    int kpos = 3072 + n;
    // Kr frag coords: d = 2*lane -> dks=lane>>3, lh=(lane>>2)&1, j=(2*lane)&7
    size_t idx = (size_t)(b*4 + hk)*524288
               + (size_t)(((kpos >> 6)*16) + (((kpos >> 5) & 1)*8) + (lane >> 3))*512
               + (size_t)((((lane >> 2) & 1) << 5) | (kpos & 31))*8
               + ((2*lane) & 7);
    *(u32*)(Kr + idx) = outp;
  }
}

// ---------------- flash attention: fragment-LDS (conflict-free), k-split waves ----------------
// grid 512: (b,hk,qt32); 8 waves = 4 heads x 2 k-halves; K+V staged once per block from
// fragment-ordered Kr/Vr (linear copy), all LDS reads lane*16-consecutive (2/bank, free).
// LDS elems: K[buf] at buf*8192; V[buf] at 16384 + buf*8192 (64 KB total, 2 blocks/CU).
__global__ void __launch_bounds__(512, 4) k_attn(
    const u16* __restrict__ q_ro, const u16* __restrict__ Kr,
    const u16* __restrict__ Vr, u16* __restrict__ attn_o)
{
  __shared__ u16 smem[32768];      // 64 KB
  __shared__ float Lsh[4][32];
  const int bid = blockIdx.x;
  const int xcd = bid & 7, idx = bid >> 3;
  const int plane = (xcd << 1) | (idx >> 5);
  const int qt = idx & 31;
  const int b = plane >> 2, hk = plane & 3;
  const int t = threadIdx.x, lane = t & 63, w = t >> 6;
  const int l31 = lane & 31, lh = lane >> 5;
  const int hf = w >> 2;           // k-half of chunk
  const int hd = w & 3;            // head within group
  const int h = hk*4 + hd;
  const int qbase = qt*32;

  const u16* qplane = q_ro + (size_t)(b*16 + h)*1024*128;
  const u16* kplane = Kr + (size_t)(b*4 + hk)*524288;
  const u16* vplane = Vr + (size_t)(b*4 + hk)*524288;

  // Q B-frags: lane holds Q[qbase+l31][dks*16 + lh*8 + j]
  bfrag qf[8];
  {
    const u16* qrow = qplane + (size_t)(qbase + l31)*128 + lh*8;
    #pragma unroll
    for (int dks = 0; dks < 8; ++dks)
      qf[dks] = *(const bfrag*)(qrow + dks*16);
  }

  const int kb0 = (qbase + 1024) & ~63;
  const int kc0 = kb0 >> 6;
  const int qpos = 3072 + qbase + l31;

  const char* smb = (const char*)smem;
  // byte read bases; frag offsets are compile-time immediates
  const int krd = hf*8192 + lane*16;            // + buf*16384 + dks*1024
  const int vrd = 32768 + hf*8192 + lane*16;    // + buf*16384 + (lks*4+dj)*1024

  f32x16 acc_o[4] = {};
  float l_run = 0.f;

  // prologue: stage chunk 0 -> buf 0 (linear copy, already fragment-ordered)
  {
    const u16* ks = kplane + (size_t)kc0*8192 + t*8;
    const u16* vs = vplane + (size_t)kc0*8192 + t*8;
    gload_lds16(ks,        smem + t*8);
    gload_lds16(ks + 4096, smem + 4096 + t*8);
    gload_lds16(vs,        smem + 16384 + t*8);
    gload_lds16(vs + 4096, smem + 20480 + t*8);
  }

  for (int c = 0; c < 33; ++c){
    __syncthreads();
    const int cur = c & 1;
    if (c < 32){
      const u16* ks = kplane + (size_t)(kc0 + c + 1)*8192 + t*8;
      const u16* vs = vplane + (size_t)(kc0 + c + 1)*8192 + t*8;
      u16* kd = smem + (cur ^ 1)*8192 + t*8;
      u16* vd = smem + 16384 + (cur ^ 1)*8192 + t*8;
      gload_lds16(ks,        kd);
      gload_lds16(ks + 4096, kd + 4096);
      gload_lds16(vs,        vd);
      gload_lds16(vs + 4096, vd + 4096);
    }

    const int kbase = krd + cur*16384;
    // S^T[k_local][q] = K_half · Q^T  (KL scale pre-folded into Q)
    f32x16 s = {};
    __builtin_amdgcn_s_setprio(1);
    #pragma unroll
    for (int dks = 0; dks < 8; ++dks){
      bfrag kf = *(const bfrag*)(smb + kbase + dks*1024);
      s = __builtin_amdgcn_mfma_f32_32x32x16_bf16(kf, qf[dks], s, 0, 0, 0);
    }
    __builtin_amdgcn_s_setprio(0);

    if ((c == 0) | (c == 32)){
      const int kb = kb0 + c*64;
      #pragma unroll
      for (int r = 0; r < 16; ++r){
        int kpos = kb + hf*32 + (r & 3) + 8*(r >> 2) + 4*lh;
        int dq = qpos - kpos;
        if ((unsigned)dq >= 2048u) s[r] = -1e30f;
      }
    }

    // p = exp2(s); l += sum(p)  (no max tracking: |s_raw*KL| <= 16.3)
    #pragma unroll
    for (int r = 0; r < 16; ++r) s[r] = exp2f(s[r]);
    {
      float a0 = (s[0]+s[1]) + (s[2]+s[3]);
      float a1 = (s[4]+s[5]) + (s[6]+s[7]);
      float a2 = (s[8]+s[9]) + (s[10]+s[11]);
      float a3 = (s[12]+s[13]) + (s[14]+s[15]);
      float lc = (a0 + a1) + (a2 + a3);
      lc += __shfl_xor(lc, 32, 64);
      l_run += lc;
    }

    // P^T B-frags via cvt_pk + permlane32_swap
    union { u32 u[4]; bfrag v; } pf[2];
    {
      u32 a0 = cvtpk(s[0],  s[1]),  a1 = cvtpk(s[2],  s[3]);
      u32 b0 = cvtpk(s[4],  s[5]),  b1 = cvtpk(s[6],  s[7]);
      swap32(a0, b0); swap32(a1, b1);
      pf[0].u[0]=a0; pf[0].u[1]=a1; pf[0].u[2]=b0; pf[0].u[3]=b1;
      u32 c0 = cvtpk(s[8],  s[9]),  c1 = cvtpk(s[10], s[11]);
      u32 e0 = cvtpk(s[12], s[13]), e1 = cvtpk(s[14], s[15]);
      swap32(c0, e0); swap32(c1, e1);
      pf[1].u[0]=c0; pf[1].u[1]=c1; pf[1].u[2]=e0; pf[1].u[3]=e1;
    }

    // O^T[d][q] += V^T · P^T  (our k columns: ks = hf*2 + lks)
    const int vbase = vrd + cur*16384;
    __builtin_amdgcn_s_setprio(1);
    #pragma unroll
    for (int lks = 0; lks < 2; ++lks)
      #pragma unroll
      for (int dj = 0; dj < 4; ++dj){
        bfrag vf = *(const bfrag*)(smb + vbase + (lks*4 + dj)*1024);
        acc_o[dj] = __builtin_amdgcn_mfma_f32_32x32x16_bf16(vf, pf[lks].v, acc_o[dj], 0, 0, 0);
      }
    __builtin_amdgcn_s_setprio(0);
  }

  // ---- merge k-halves through LDS (alias K area; 2 passes x 2 heads, 32 KB) ----
  #pragma unroll
  for (int p = 0; p < 2; ++p){
    __syncthreads();
    if (hf == 1 && (hd >> 1) == p){
      if (lh == 0) Lsh[hd][l31] = l_run;
      float* om = (float*)smem + (hd & 1)*4096;
      #pragma unroll
      for (int dj = 0; dj < 4; ++dj)
        #pragma unroll
        for (int rg = 0; rg < 4; ++rg){
          int slot = dj*8 + rg*2 + lh;
          f32x4 vv;
          #pragma unroll
          for (int j = 0; j < 4; ++j) vv[j] = acc_o[dj][rg*4 + j];
          *(f32x4*)&om[l31*128 + ((slot ^ (l31 & 7)) << 2)] = vv;
        }
    }
    __syncthreads();
    if (hf == 0 && (hd >> 1) == p){
      const float* om = (const float*)smem + (hd & 1)*4096;
      float ltot = l_run + Lsh[hd][l31];
      float inv = 1.0f / ltot;
      const int bn = b*1024 + qbase + l31;
      u16* orow = attn_o + (size_t)bn*2048 + h*128;
      #pragma unroll
      for (int dj = 0; dj < 4; ++dj)
        #pragma unroll
        for (int rg = 0; rg < 4; ++rg){
          int slot = dj*8 + rg*2 + lh;
          f32x4 vv = *(const f32x4*)&om[l31*128 + ((slot ^ (l31 & 7)) << 2)];
          int d0 = dj*32 + rg*8 + lh*4;
          u16x4 o;
          #pragma unroll
          for (int j = 0; j < 4; ++j) o[j] = f2bf((acc_o[dj][rg*4 + j] + vv[j])*inv);
          *(u16x4*)(orow + d0) = o;
        }
    }
  }
}

// ---------------- launch ----------------
extern "C" void kernel_launch(void* const* d_in, const int* in_sizes, int n_in,
                              void* d_out, int out_size, void* d_ws, size_t ws_size,
                              hipStream_t stream)
{
  const float* x      = (const float*)d_in[0];
  const float* past_k = (const float*)d_in[1];
  const float* past_v = (const float*)d_in[2];
  const float* fcos   = (const float*)d_in[3];
  const float* fsin   = (const float*)d_in[4];
  const float* Wq     = (const float*)d_in[5];
  const float* Wk     = (const float*)d_in[6];
  const float* Wv     = (const float*)d_in[7];
  const float* Wo     = (const float*)d_in[8];
  const float* bo     = (const float*)d_in[9];
  const float* wqn    = (const float*)d_in[10];
  const float* wkn    = (const float*)d_in[11];
  float* out = (float*)d_out;
  char* ws = (char*)d_ws;

  u16* xb    = (u16*)(ws);                 // 16.8 MB
  u16* wqkv  = (u16*)(ws + 16777216);      // 12.6 MB
  u16* wo_b  = (u16*)(ws + 29360128);      // 8.4 MB
  u16* q_ro  = (u16*)(ws + 37748736);      // 16.8 MB
  u16* Kr    = (u16*)(ws + 54525952);      // 16.8 MB
  u16* Vr    = (u16*)(ws + 71303168);      // 16.8 MB
  u16* v_new = (u16*)(ws + 88080384);      // 4.2 MB
  u16* proj  = (u16*)(ws + 92274688);      // 25.2 MB (attn_o aliases)
  u16* attn_o = proj;

  k_cvt<<<8192, 256, 0, stream>>>(x, xb, 2097152);
  k_cvt<<<4096, 256, 0, stream>>>(Wq, wqkv, 1048576);
  k_cvt<<<1024, 256, 0, stream>>>(Wk, wqkv + 2048*2048, 262144);
  k_cvt<<<1024, 256, 0, stream>>>(Wv, wqkv + 2560*2048, 262144);
  k_cvt<<<4096, 256, 0, stream>>>(Wo, wo_b, 1048576);
  k_past_kr<<<dim3(32, 16), 256, 0, stream>>>(past_k, Kr);
  k_past_vr<<<dim3(32, 16), 256, 0, stream>>>(past_v, Vr);

  k_gemm<0><<<dim3(24, 32), 256, 0, stream>>>(xb, wqkv, proj, nullptr, nullptr, 4096, 3072, 2048);
  k_rmsrope<<<dim3(4096, 6), 256, 0, stream>>>(proj, fcos, fsin, wqn, wkn, q_ro, Kr, v_new);
  k_new_vr<<<dim3(16, 16), 256, 0, stream>>>(v_new, Vr);
  k_attn<<<512, 512, 0, stream>>>(q_ro, Kr, Vr, attn_o);
  k_gemm<1><<<dim3(16, 32), 256, 0, stream>>>(attn_o, wo_b, nullptr, out, bo, 4096, 2048, 2048);
}

// Round 8
// 255.144 us; speedup vs baseline: 1.5752x; 1.0195x over previous
//
#include <hip/hip_runtime.h>
#include <hip/hip_bf16.h>
#include <stdint.h>

typedef unsigned short u16;
typedef unsigned int u32;
typedef __attribute__((ext_vector_type(8))) __bf16 bfrag;
typedef __attribute__((ext_vector_type(4))) float f32x4;
typedef __attribute__((ext_vector_type(16))) float f32x16;
typedef __attribute__((ext_vector_type(4))) unsigned short u16x4;

__device__ __forceinline__ u16 f2bf(float f){
  union { float f; u32 u; } v; v.f = f;
  u32 u = v.u;
  return (u16)((u + 0x7fffu + ((u >> 16) & 1u)) >> 16);
}

__device__ __forceinline__ u32 cvtpk(float a, float b){
  u32 r; asm("v_cvt_pk_bf16_f32 %0, %1, %2" : "=v"(r) : "v"(a), "v"(b)); return r;
}
__device__ __forceinline__ void swap32(u32 &a, u32 &b){
  asm volatile("v_permlane32_swap_b32 %0, %1" : "+v"(a), "+v"(b));
}

__device__ __forceinline__ void gload_lds16(const void* g, void* l){
  __builtin_amdgcn_global_load_lds(
      (__attribute__((address_space(1))) void*)(unsigned long long)g,
      (__attribute__((address_space(3))) void*)(u32)(unsigned long long)l,
      16, 0, 0);
}

// ---------------- converts ----------------
__global__ void __launch_bounds__(256) k_cvt(const float* __restrict__ s, u16* __restrict__ d, int n4){
  int i = blockIdx.x*256 + threadIdx.x;
  if (i >= n4) return;
  float4 v = ((const float4*)s)[i];
  u16x4 o; o[0]=f2bf(v.x); o[1]=f2bf(v.y); o[2]=f2bf(v.z); o[3]=f2bf(v.w);
  ((u16x4*)d)[i] = o;
}

// past_k f32 [pl][3072][128] -> Kr fragment layout, kc 16..47
// Kr elem: [pl][kc<64][fhi=hf*8+dks][lane64][8]  (frag = K[kc*64+hf*32+(lane&31)][dks*16+(lane>>5)*8 + j])
__global__ void __launch_bounds__(256) k_past_kr(const float* __restrict__ pk, u16* __restrict__ Kr){
  __shared__ u16 TK[64][128];
  const int kc = 16 + blockIdx.x;
  const int pl = blockIdx.y;
  const int t = threadIdx.x;
  const float* src = pk + (size_t)pl*393216 + (size_t)kc*8192;
  #pragma unroll
  for (int i = 0; i < 8; ++i){
    int e = i*1024 + t*4;
    float4 v = *(const float4*)(src + e);
    u16x4 o; o[0]=f2bf(v.x); o[1]=f2bf(v.y); o[2]=f2bf(v.z); o[3]=f2bf(v.w);
    *(u16x4*)&TK[e>>7][e&127] = o;
  }
  __syncthreads();
  u16* dst = Kr + (size_t)pl*524288 + (size_t)kc*8192;
  #pragma unroll
  for (int i = 0; i < 4; ++i){
    int f = i*256 + t;
    int fhi = f >> 6, lf = f & 63;
    int row = ((f >> 9) << 5) | (lf & 31);           // hf*32 + l31
    int col = ((fhi & 7) << 4) | ((lf >> 5) << 3);   // dks*16 + lh*8
    bfrag v = *(const bfrag*)&TK[row][col];
    *(bfrag*)(dst + fhi*512 + lf*8) = v;
  }
}

// past_v f32 [pl][3072][128] -> Vr fragment layout, kc 16..47
// Vr elem: [pl][kc][ghi=hf*8+lks*4+dj][lane64][8] (frag = V[kc*64+hf*32+lks*16+(lane>>5)*8+j][dj*32+(lane&31)])
__global__ void __launch_bounds__(256) k_past_vr(const float* __restrict__ pv, u16* __restrict__ Vr){
  __shared__ u16 T2[128][80];
  const int kc = 16 + blockIdx.x;
  const int pl = blockIdx.y;
  const int t = threadIdx.x;
  const float* src = pv + (size_t)pl*393216 + (size_t)kc*8192;
  #pragma unroll
  for (int i = 0; i < 8; ++i){
    int e = i*1024 + t*4;
    int row = e >> 7, d0 = e & 127;
    float4 v = *(const float4*)(src + e);
    T2[d0][row]   = f2bf(v.x);
    T2[d0+1][row] = f2bf(v.y);
    T2[d0+2][row] = f2bf(v.z);
    T2[d0+3][row] = f2bf(v.w);
  }
  __syncthreads();
  u16* dst = Vr + (size_t)pl*524288 + (size_t)kc*8192;
  #pragma unroll
  for (int i = 0; i < 4; ++i){
    int g = i*256 + t;
    int ghi = g >> 6, lg = g & 63;
    int d  = ((ghi & 3) << 5) | (lg & 31);                            // dj*32 + l31
    int k0 = ((g >> 9) << 5) | (((ghi >> 2) & 1) << 4) | ((lg >> 5) << 3); // hf*32+lks*16+lh*8
    bfrag v = *(const bfrag*)&T2[d][k0];
    *(bfrag*)(dst + ghi*512 + lg*8) = v;
  }
}

// v_new bf16 [pl][1024][128] -> Vr, kc 48..63
__global__ void __launch_bounds__(256) k_new_vr(const u16* __restrict__ vn, u16* __restrict__ Vr){
  __shared__ u16 T2[128][80];
  const int kcl = blockIdx.x;   // 0..15
  const int pl = blockIdx.y;
  const int t = threadIdx.x;
  const u16* src = vn + (size_t)pl*131072 + (size_t)kcl*8192;
  #pragma unroll
  for (int i = 0; i < 4; ++i){
    int e = i*2048 + t*8;
    int row = e >> 7, d0 = e & 127;
    union { bfrag v; u16 x[8]; } u;
    u.v = *(const bfrag*)(src + e);
    #pragma unroll
    for (int j = 0; j < 8; ++j) T2[d0+j][row] = u.x[j];
  }
  __syncthreads();
  u16* dst = Vr + (size_t)pl*524288 + (size_t)(48 + kcl)*8192;
  #pragma unroll
  for (int i = 0; i < 4; ++i){
    int g = i*256 + t;
    int ghi = g >> 6, lg = g & 63;
    int d  = ((ghi & 3) << 5) | (lg & 31);
    int k0 = ((g >> 9) << 5) | (((ghi >> 2) & 1) << 4) | ((lg >> 5) << 3);
    bfrag v = *(const bfrag*)&T2[d][k0];
    *(bfrag*)(dst + ghi*512 + lg*8) = v;
  }
}

// ---------------- GEMM C[M][N] = A[M][K] * B[N][K]^T ----------------
template<int EPI>
__global__ void __launch_bounds__(256) k_gemm(
    const u16* __restrict__ A, const u16* __restrict__ Bm,
    u16* __restrict__ Cb, float* __restrict__ Cf, const float* __restrict__ bias,
    int M, int Nn, int K)
{
  __shared__ u16 lsA[2][4096];
  __shared__ u16 lsB[2][4096];
  const int t = threadIdx.x, lane = t & 63, wid = t >> 6;
  const int l15 = lane & 15, l4 = lane >> 4;
  const int wm = wid >> 1, wn = wid & 1;
  const int bn = blockIdx.x, bm = blockIdx.y;
  const u16* Ab = A + (size_t)bm*128*K;
  const u16* Bb = Bm + (size_t)bn*128*K;

  auto stage = [&](u16* ls, const u16* g, int kof){
    #pragma unroll
    for (int r = 0; r < 2; ++r){
      int row = r*64 + (t >> 2);
      int s = (t & 3) ^ ((row >> 1) & 3);
      gload_lds16(g + (size_t)row*K + kof + s*8, ls + r*2048 + wid*512);
    }
  };

  f32x4 acc[4][4] = {};
  stage(&lsA[0][0], Ab, 0);
  stage(&lsB[0][0], Bb, 0);
  const int NT = K >> 5;
  const int sl = l4 ^ ((l15 >> 1) & 3);
  const int ra0 = wm*64 + l15, rb0 = wn*64 + l15;
  for (int kt = 0; kt < NT; ++kt){
    __syncthreads();
    const int cur = kt & 1;
    if (kt + 1 < NT){
      stage(&lsA[cur ^ 1][0], Ab, (kt + 1)*32);
      stage(&lsB[cur ^ 1][0], Bb, (kt + 1)*32);
    }
    bfrag af[4], bfv[4];
    #pragma unroll
    for (int i = 0; i < 4; ++i){
      af[i]  = *(const bfrag*)&lsA[cur][(ra0 + i*16)*32 + sl*8];
      bfv[i] = *(const bfrag*)&lsB[cur][(rb0 + i*16)*32 + sl*8];
    }
    #pragma unroll
    for (int i = 0; i < 4; ++i)
      #pragma unroll
      for (int j = 0; j < 4; ++j)
        acc[i][j] = __builtin_amdgcn_mfma_f32_16x16x32_bf16(af[i], bfv[j], acc[i][j], 0, 0, 0);
  }
  const int row0 = bm*128 + wm*64, col0 = bn*128 + wn*64;
  #pragma unroll
  for (int i = 0; i < 4; ++i)
    #pragma unroll
    for (int j = 0; j < 4; ++j){
      int cc = col0 + j*16 + l15;
      float bv = (EPI == 1) ? bias[cc] : 0.f;
      #pragma unroll
      for (int r = 0; r < 4; ++r){
        int rr = row0 + i*16 + l4*4 + r;
        if (EPI == 0) Cb[(size_t)rr*Nn + cc] = f2bf(acc[i][j][r]);
        else          Cf[(size_t)rr*Nn + cc] = acc[i][j][r] + bv;
      }
    }
}

// ---------------- fused RMSNorm + RoPE + scatter ----------------
// q: row-major q_ro (pre-scaled by log2e/sqrt(D)); k: scattered into Kr frags; v: rows into v_new
__global__ void __launch_bounds__(256) k_rmsrope(
    const u16* __restrict__ proj, const float* __restrict__ cosb, const float* __restrict__ sinb,
    const float* __restrict__ wq, const float* __restrict__ wk,
    u16* __restrict__ q_ro, u16* __restrict__ Kr, u16* __restrict__ v_new)
{
  const int bn = blockIdx.x;
  const int b = bn >> 10, n = bn & 1023;
  const int lane = threadIdx.x & 63, w = threadIdx.x >> 6;
  const int chunk = blockIdx.y*4 + w;
  const u16* src = proj + (size_t)bn*3072 + chunk*128 + lane*2;
  const u32 raw = *(const u32*)src;
  union { u32 u; float f; } a, c2;
  a.u = raw << 16; c2.u = raw & 0xffff0000u;
  float x0 = a.f, x1 = c2.f;
  if (chunk >= 20){
    int hk = chunk - 20;
    *(u32*)(v_new + ((size_t)(b*4 + hk)*1024 + n)*128 + lane*2) = raw;
    return;
  }
  float ss = x0*x0 + x1*x1;
  #pragma unroll
  for (int m = 1; m < 64; m <<= 1) ss += __shfl_xor(ss, m, 64);
  float inv = rsqrtf(ss*(1.f/128.f) + 1e-6f);
  const float* wn2 = (chunk < 16) ? wq : wk;
  x0 *= inv*wn2[lane*2]; x1 *= inv*wn2[lane*2 + 1];
  float cz = cosb[n*64 + lane], sz = sinb[n*64 + lane];
  float r0 = x0*cz - x1*sz;
  float r1 = x0*sz + x1*cz;
  if (chunk < 16){
    const float KLF = 0.127529904f;   // log2(e)/sqrt(128) folded into q
    r0 *= KLF; r1 *= KLF;
    u32 outp = (u32)f2bf(r0) | ((u32)f2bf(r1) << 16);
    *(u32*)(q_ro + (((size_t)(b*16 + chunk)*1024 + n) << 7) + lane*2) = outp;
  } else {
    int hk = chunk - 16;
    u32 outp = (u32)f2bf(r0) | ((u32)f2bf(r1) << 16);
    int kpos = 3072 + n;
    // Kr frag coords: d = 2*lane -> dks=lane>>3, lh=(lane>>2)&1, j=(2*lane)&7
    size_t idx = (size_t)(b*4 + hk)*524288
               + (size_t)(((kpos >> 6)*16) + (((kpos >> 5) & 1)*8) + (lane >> 3))*512
               + (size_t)((((lane >> 2) & 1) << 5) | (kpos & 31))*8
               + ((2*lane) & 7);
    *(u32*)(Kr + idx) = outp;
  }
}

// ---------------- flash attention: fragment-LDS, software-pipelined QK(c+1) || SM(c)+PV(c) ----------------
// grid 512: (b,hk,qt32); 8 waves = 4 heads x 2 k-halves.
// K staged 2 ahead, V staged 1 ahead, in 2x2 LDS buffers; one barrier per chunk.
// Matrix pipe gets QK(c+1)+PV(c) queued while softmax(c) runs on VALU concurrently.
__global__ void __launch_bounds__(512, 2) k_attn(
    const u16* __restrict__ q_ro, const u16* __restrict__ Kr,
    const u16* __restrict__ Vr, u16* __restrict__ attn_o)
{
  __shared__ u16 smem[32768];      // 64 KB: kbuf[2] at elem 0/8192; vbuf[2] at 16384/24576
  __shared__ float Lsh[4][32];
  const int bid = blockIdx.x;
  const int xcd = bid & 7, idx = bid >> 3;
  const int plane = (xcd << 1) | (idx >> 5);
  const int qt = idx & 31;
  const int b = plane >> 2, hk = plane & 3;
  const int t = threadIdx.x, lane = t & 63, w = t >> 6;
  const int l31 = lane & 31, lh = lane >> 5;
  const int hf = w >> 2;           // k-half of chunk
  const int hd = w & 3;            // head within group
  const int h = hk*4 + hd;
  const int qbase = qt*32;

  const u16* qplane = q_ro + (size_t)(b*16 + h)*1024*128;
  const u16* kplane = Kr + (size_t)(b*4 + hk)*524288;
  const u16* vplane = Vr + (size_t)(b*4 + hk)*524288;

  // Q B-frags: lane holds Q[qbase+l31][dks*16 + lh*8 + j]
  bfrag qf[8];
  {
    const u16* qrow = qplane + (size_t)(qbase + l31)*128 + lh*8;
    #pragma unroll
    for (int dks = 0; dks < 8; ++dks)
      qf[dks] = *(const bfrag*)(qrow + dks*16);
  }

  const int kb0 = (qbase + 1024) & ~63;
  const int kc0 = kb0 >> 6;
  const int qpos = 3072 + qbase + l31;

  const char* smb = (const char*)smem;
  const int krd = hf*8192 + lane*16;            // + buf*16384 + dks*1024
  const int vrd = 32768 + hf*8192 + lane*16;    // + buf*16384 + (lks*4+dj)*1024

  auto stageK = [&](int c2, int buf){
    const u16* ks = kplane + (size_t)(kc0 + c2)*8192 + t*8;
    gload_lds16(ks,        smem + buf*8192 + t*8);
    gload_lds16(ks + 4096, smem + buf*8192 + 4096 + t*8);
  };
  auto stageV = [&](int c2, int buf){
    const u16* vs = vplane + (size_t)(kc0 + c2)*8192 + t*8;
    gload_lds16(vs,        smem + 16384 + buf*8192 + t*8);
    gload_lds16(vs + 4096, smem + 16384 + buf*8192 + 4096 + t*8);
  };

  f32x16 acc_o[4] = {};
  float l_run = 0.f;

  // prologue: K(0)->kbuf0, K(1)->kbuf1, V(0)->vbuf0; then QK(0)->sA
  stageK(0, 0); stageK(1, 1); stageV(0, 0);
  __syncthreads();

  f32x16 sA, sB;
  {
    #pragma unroll
    for (int r = 0; r < 16; ++r) sA[r] = 0.f;
    __builtin_amdgcn_s_setprio(1);
    #pragma unroll
    for (int dks = 0; dks < 8; ++dks){
      bfrag kf = *(const bfrag*)(smb + krd + dks*1024);
      sA = __builtin_amdgcn_mfma_f32_32x32x16_bf16(kf, qf[dks], sA, 0, 0, 0);
    }
    __builtin_amdgcn_s_setprio(0);
  }

  // iteration c: softmax+PV chunk c (sCur), issue QK(c+1) into sNxt
  auto body = [&](int c, f32x16& sCur, f32x16& sNxt){
    __syncthreads();
    if (c <= 30) stageK(c + 2, c & 1);          // kbuf[c&1] held K(c), consumed at iter c-1
    if (c <= 31) stageV(c + 1, (c + 1) & 1);    // vbuf[(c+1)&1] held V(c-1), consumed at iter c-1

    // QK(c+1) -> sNxt (matrix pipe fills; wave continues issuing VALU below)
    if (c < 32){
      #pragma unroll
      for (int r = 0; r < 16; ++r) sNxt[r] = 0.f;
      const int kbase = krd + ((c + 1) & 1)*16384;
      __builtin_amdgcn_s_setprio(1);
      #pragma unroll
      for (int dks = 0; dks < 8; ++dks){
        bfrag kf = *(const bfrag*)(smb + kbase + dks*1024);
        sNxt = __builtin_amdgcn_mfma_f32_32x32x16_bf16(kf, qf[dks], sNxt, 0, 0, 0);
      }
      __builtin_amdgcn_s_setprio(0);
    }

    // V frags for PV(c) issued early (latency hides under softmax)
    bfrag vf[8];
    const int vbase = vrd + (c & 1)*16384;
    #pragma unroll
    for (int g = 0; g < 8; ++g) vf[g] = *(const bfrag*)(smb + vbase + g*1024);

    if ((c == 0) | (c == 32)){
      const int kb = kb0 + c*64;
      #pragma unroll
      for (int r = 0; r < 16; ++r){
        int kpos = kb + hf*32 + (r & 3) + 8*(r >> 2) + 4*lh;
        int dq = qpos - kpos;
        if ((unsigned)dq >= 2048u) sCur[r] = -1e30f;
      }
    }

    // p = exp2(s); l += sum(p)  (no max tracking: |s_raw*KL| <= 16.3)
    #pragma unroll
    for (int r = 0; r < 16; ++r) sCur[r] = exp2f(sCur[r]);
    {
      float a0 = (sCur[0]+sCur[1]) + (sCur[2]+sCur[3]);
      float a1 = (sCur[4]+sCur[5]) + (sCur[6]+sCur[7]);
      float a2 = (sCur[8]+sCur[9]) + (sCur[10]+sCur[11]);
      float a3 = (sCur[12]+sCur[13]) + (sCur[14]+sCur[15]);
      float lc = (a0 + a1) + (a2 + a3);
      lc += __shfl_xor(lc, 32, 64);
      l_run += lc;
    }

    // P^T B-frags via cvt_pk + permlane32_swap
    union { u32 u[4]; bfrag v; } pf[2];
    {
      u32 a0 = cvtpk(sCur[0],  sCur[1]),  a1 = cvtpk(sCur[2],  sCur[3]);
      u32 b0 = cvtpk(sCur[4],  sCur[5]),  b1 = cvtpk(sCur[6],  sCur[7]);
      swap32(a0, b0); swap32(a1, b1);
      pf[0].u[0]=a0; pf[0].u[1]=a1; pf[0].u[2]=b0; pf[0].u[3]=b1;
      u32 c0 = cvtpk(sCur[8],  sCur[9]),  c1 = cvtpk(sCur[10], sCur[11]);
      u32 e0 = cvtpk(sCur[12], sCur[13]), e1 = cvtpk(sCur[14], sCur[15]);
      swap32(c0, e0); swap32(c1, e1);
      pf[1].u[0]=c0; pf[1].u[1]=c1; pf[1].u[2]=e0; pf[1].u[3]=e1;
    }

    // O^T[d][q] += V^T · P^T
    __builtin_amdgcn_s_setprio(1);
    #pragma unroll
    for (int lks = 0; lks < 2; ++lks)
      #pragma unroll
      for (int dj = 0; dj < 4; ++dj)
        acc_o[dj] = __builtin_amdgcn_mfma_f32_32x32x16_bf16(vf[lks*4 + dj], pf[lks].v, acc_o[dj], 0, 0, 0);
    __builtin_amdgcn_s_setprio(0);
  };

  #pragma unroll 1
  for (int cc = 0; cc < 16; ++cc){
    body(2*cc,     sA, sB);
    body(2*cc + 1, sB, sA);
  }
  body(32, sA, sB);

  // ---- merge k-halves through LDS (alias kbuf area; 2 passes x 2 heads) ----
  #pragma unroll
  for (int p = 0; p < 2; ++p){
    __syncthreads();
    if (hf == 1 && (hd >> 1) == p){
      if (lh == 0) Lsh[hd][l31] = l_run;
      float* om = (float*)smem + (hd & 1)*4096;
      #pragma unroll
      for (int dj = 0; dj < 4; ++dj)
        #pragma unroll
        for (int rg = 0; rg < 4; ++rg){
          int slot = dj*8 + rg*2 + lh;
          f32x4 vv;
          #pragma unroll
          for (int j = 0; j < 4; ++j) vv[j] = acc_o[dj][rg*4 + j];
          *(f32x4*)&om[l31*128 + ((slot ^ (l31 & 7)) << 2)] = vv;
        }
    }
    __syncthreads();
    if (hf == 0 && (hd >> 1) == p){
      const float* om = (const float*)smem + (hd & 1)*4096;
      float ltot = l_run + Lsh[hd][l31];
      float inv = 1.0f / ltot;
      const int bn = b*1024 + qbase + l31;
      u16* orow = attn_o + (size_t)bn*2048 + h*128;
      #pragma unroll
      for (int dj = 0; dj < 4; ++dj)
        #pragma unroll
        for (int rg = 0; rg < 4; ++rg){
          int slot = dj*8 + rg*2 + lh;
          f32x4 vv = *(const f32x4*)&om[l31*128 + ((slot ^ (l31 & 7)) << 2)];
          int d0 = dj*32 + rg*8 + lh*4;
          u16x4 o;
          #pragma unroll
          for (int j = 0; j < 4; ++j) o[j] = f2bf((acc_o[dj][rg*4 + j] + vv[j])*inv);
          *(u16x4*)(orow + d0) = o;
        }
    }
  }
}

// ---------------- launch ----------------
extern "C" void kernel_launch(void* const* d_in, const int* in_sizes, int n_in,
                              void* d_out, int out_size, void* d_ws, size_t ws_size,
                              hipStream_t stream)
{
  const float* x      = (const float*)d_in[0];
  const float* past_k = (const float*)d_in[1];
  const float* past_v = (const float*)d_in[2];
  const float* fcos   = (const float*)d_in[3];
  const float* fsin   = (const float*)d_in[4];
  const float* Wq     = (const float*)d_in[5];
  const float* Wk     = (const float*)d_in[6];
  const float* Wv     = (const float*)d_in[7];
  const float* Wo     = (const float*)d_in[8];
  const float* bo     = (const float*)d_in[9];
  const float* wqn    = (const float*)d_in[10];
  const float* wkn    = (const float*)d_in[11];
  float* out = (float*)d_out;
  char* ws = (char*)d_ws;

  u16* xb    = (u16*)(ws);                 // 16.8 MB
  u16* wqkv  = (u16*)(ws + 16777216);      // 12.6 MB
  u16* wo_b  = (u16*)(ws + 29360128);      // 8.4 MB
  u16* q_ro  = (u16*)(ws + 37748736);      // 16.8 MB
  u16* Kr    = (u16*)(ws + 54525952);      // 16.8 MB
  u16* Vr    = (u16*)(ws + 71303168);      // 16.8 MB
  u16* v_new = (u16*)(ws + 88080384);      // 4.2 MB
  u16* proj  = (u16*)(ws + 92274688);      // 25.2 MB (attn_o aliases)
  u16* attn_o = proj;

  k_cvt<<<8192, 256, 0, stream>>>(x, xb, 2097152);
  k_cvt<<<4096, 256, 0, stream>>>(Wq, wqkv, 1048576);
  k_cvt<<<1024, 256, 0, stream>>>(Wk, wqkv + 2048*2048, 262144);
  k_cvt<<<1024, 256, 0, stream>>>(Wv, wqkv + 2560*2048, 262144);
  k_cvt<<<4096, 256, 0, stream>>>(Wo, wo_b, 1048576);
  k_past_kr<<<dim3(32, 16), 256, 0, stream>>>(past_k, Kr);
  k_past_vr<<<dim3(32, 16), 256, 0, stream>>>(past_v, Vr);

  k_gemm<0><<<dim3(24, 32), 256, 0, stream>>>(xb, wqkv, proj, nullptr, nullptr, 4096, 3072, 2048);
  k_rmsrope<<<dim3(4096, 6), 256, 0, stream>>>(proj, fcos, fsin, wqn, wkn, q_ro, Kr, v_new);
  k_new_vr<<<dim3(16, 16), 256, 0, stream>>>(v_new, Vr);
  k_attn<<<512, 512, 0, stream>>>(q_ro, Kr, Vr, attn_o);
  k_gemm<1><<<dim3(16, 32), 256, 0, stream>>>(attn_o, wo_b, nullptr, out, bo, 4096, 2048, 2048);
}